// Round 3
// baseline (1608.144 us; speedup 1.0000x reference)
//
#include <hip/hip_runtime.h>
#include <hip/hip_bf16.h>
#include <cstddef>

#define B_ 4
#define S_ 1024
#define E_ 1024
#define H_ 16
#define D_ 64
#define BH_ (B_*H_)

// ---------------------------------------------------------------------------
// fp32 GEMM: C[m,n] = sum_k X[m,k] * W[n,k] + bias[n]; X: Mx1024, W: 1024x1024
// mode 0: outF fp32, heads layout [(b*H+h)*S + s]*64 + c
// mode 1: outF fp32, natural layout m*1024 + n
// mode 2: no store; t2g[bh][c] += sum_rows (C + bias)   (p2 reduction, fused)
// Tile 64x64 per 256-thread block; 4x4 accumulators per thread; K-chunk 16.
// ---------------------------------------------------------------------------
__global__ __launch_bounds__(256) void gemm_f32(
    const float* __restrict__ X, const float* __restrict__ W,
    const float* __restrict__ bias, float* __restrict__ outF,
    float* __restrict__ t2g, int mode)
{
    const int K = 1024;
    __shared__ float Xs[16][68];   // [k][m], pad 68 to break conflicts
    __shared__ float Ws[16][68];   // [k][n]
    __shared__ float tred[64];

    const int tid = threadIdx.x;
    const int tx = tid & 15, ty = tid >> 4;      // n-group, m-group
    const int bm = blockIdx.x, bn = blockIdx.y;

    const int lr = tid >> 2;          // 0..63: staging row
    const int lk = (tid & 3) * 4;     // 0,4,8,12: staging k-offset

    const float* xg = X + (size_t)(bm * 64 + lr) * K + lk;
    const float* wg = W + (size_t)(bn * 64 + lr) * K + lk;

    float acc[4][4] = {};

    for (int k0 = 0; k0 < K; k0 += 16) {
        float4 xv = *(const float4*)(xg + k0);
        float4 wv = *(const float4*)(wg + k0);
        __syncthreads();
        Xs[lk + 0][lr] = xv.x; Xs[lk + 1][lr] = xv.y;
        Xs[lk + 2][lr] = xv.z; Xs[lk + 3][lr] = xv.w;
        Ws[lk + 0][lr] = wv.x; Ws[lk + 1][lr] = wv.y;
        Ws[lk + 2][lr] = wv.z; Ws[lk + 3][lr] = wv.w;
        __syncthreads();
#pragma unroll
        for (int k = 0; k < 16; ++k) {
            float4 a4 = *(const float4*)&Xs[k][ty * 4];
            float4 b4 = *(const float4*)&Ws[k][tx * 4];
            float am[4] = {a4.x, a4.y, a4.z, a4.w};
            float bv[4] = {b4.x, b4.y, b4.z, b4.w};
#pragma unroll
            for (int i = 0; i < 4; ++i)
#pragma unroll
                for (int j = 0; j < 4; ++j)
                    acc[i][j] = fmaf(am[i], bv[j], acc[i][j]);
        }
    }

    if (mode == 2) {
        if (tid < 64) tred[tid] = 0.f;
        __syncthreads();
        int bh = (bm >> 4) * H_ + bn;   // 16 m-tiles per batch; n-tile == head
#pragma unroll
        for (int j = 0; j < 4; ++j) {
            int c = tx * 4 + j;
            float s = 4.0f * bias[bn * 64 + c];   // 4 rows of bias per thread
#pragma unroll
            for (int i = 0; i < 4; ++i) s += acc[i][j];
            atomicAdd(&tred[c], s);
        }
        __syncthreads();
        if (tid < 64) atomicAdd(&t2g[bh * 64 + tid], tred[tid]);
        return;
    }

#pragma unroll
    for (int i = 0; i < 4; ++i) {
        int m = bm * 64 + ty * 4 + i;
#pragma unroll
        for (int j = 0; j < 4; ++j) {
            int n = bn * 64 + tx * 4 + j;
            float val = acc[i][j] + bias[n];
            if (mode == 0) {
                int b = m >> 10, s = m & 1023, h = n >> 6, c = n & 63;
                outF[((size_t)(b * H_ + h) * S_ + s) * D_ + c] = val;
            } else {
                outF[(size_t)m * 1024 + n] = val;
            }
        }
    }
}

__global__ void zero_t2(float* __restrict__ t2)
{
    t2[blockIdx.x * 64 + threadIdx.x] = 0.f;
}

// M[bh][a][c] = (1/8) * sum_d A[a][c][d] * t2[bh][d]   (fold 1/sqrt(64))
__global__ void compute_M(const float* __restrict__ A, const float* __restrict__ t2,
                          float* __restrict__ Mout)
{
    int bh = blockIdx.x;
    __shared__ float ts[64];
    if (threadIdx.x < 64) ts[threadIdx.x] = t2[bh * 64 + threadIdx.x];
    __syncthreads();
    int c = threadIdx.x & 63;
    int a0 = (threadIdx.x >> 6) * 16;
    for (int a = a0; a < a0 + 16; ++a) {
        float s = 0.f;
        const float* Ap = A + ((size_t)a * 64 + c) * 64;
#pragma unroll 8
        for (int d = 0; d < 64; ++d) s = fmaf(Ap[d], ts[d], s);
        Mout[((size_t)bh * 64 + a) * 64 + c] = s * 0.125f;
    }
}

// q[bh][i][c] = sum_a p0[bh][i][a] * M[bh][a][c] -- IN PLACE over p0.
__global__ __launch_bounds__(256) void compute_q(
    float* __restrict__ pq, const float* __restrict__ Min)
{
    int bh = blockIdx.y, i0 = blockIdx.x * 16;
    __shared__ float Ms[4096];
    __shared__ float p0s[16 * 64];
    float* base = pq + ((size_t)bh * S_ + i0) * 64;
    for (int t = threadIdx.x; t < 4096; t += 256) Ms[t] = Min[(size_t)bh * 4096 + t];
    for (int t = threadIdx.x; t < 1024; t += 256) p0s[t] = base[t];
    __syncthreads();
    int c = threadIdx.x & 63, il = threadIdx.x >> 6;
#pragma unroll
    for (int rr = 0; rr < 4; ++rr) {
        int ilocal = rr * 4 + il;
        const float* p0r = &p0s[ilocal * 64];
        float s = 0.f;
#pragma unroll 8
        for (int a = 0; a < 64; ++a) s = fmaf(p0r[a], Ms[a * 64 + c], s);
        base[(size_t)ilocal * 64 + c] = s;
    }
}

// logits[i][j] = sum_c q[i][c]*p1[j][c]; softmax over j; fp32 attn out.
// Block: 16 rows of one (b,h); wave w owns rows 4w..4w+3; lane = col within tile.
__global__ __launch_bounds__(256) void logits_softmax(
    const float* __restrict__ q, const float* __restrict__ p1, float* __restrict__ attn)
{
    int bh = blockIdx.y, i0 = blockIdx.x * 16;
    int tid = threadIdx.x, w = tid >> 6, lane = tid & 63;
    __shared__ float qs[16 * 64];
    __shared__ float p1s[64 * 65];

    for (int t = tid; t < 16 * 64; t += 256)
        qs[t] = q[((size_t)bh * S_ + i0) * 64 + t];

    float L[4][16];
    for (int tile = 0; tile < 16; ++tile) {
        __syncthreads();
        {   // stage p1 tile (64 x 64 fp32)
            int jl = tid >> 2, c0 = (tid & 3) * 16;
            const float* src = p1 + ((size_t)bh * S_ + tile * 64 + jl) * 64 + c0;
#pragma unroll
            for (int k = 0; k < 16; k += 4) {
                float4 v4 = *(const float4*)&src[k];
                p1s[jl * 65 + c0 + k + 0] = v4.x;
                p1s[jl * 65 + c0 + k + 1] = v4.y;
                p1s[jl * 65 + c0 + k + 2] = v4.z;
                p1s[jl * 65 + c0 + k + 3] = v4.w;
            }
        }
        __syncthreads();
#pragma unroll
        for (int rr = 0; rr < 4; ++rr) {
            const float* qrow = &qs[(w * 4 + rr) * 64];
            const float* prow = &p1s[lane * 65];
            float s = 0.f;
#pragma unroll
            for (int c = 0; c < 64; ++c) s = fmaf(qrow[c], prow[c], s);
            L[rr][tile] = s;
        }
    }

#pragma unroll
    for (int rr = 0; rr < 4; ++rr) {
        float m = L[rr][0];
#pragma unroll
        for (int t = 1; t < 16; ++t) m = fmaxf(m, L[rr][t]);
#pragma unroll
        for (int off = 1; off < 64; off <<= 1) m = fmaxf(m, __shfl_xor(m, off, 64));
        float sum = 0.f;
#pragma unroll
        for (int t = 0; t < 16; ++t) { L[rr][t] = __expf(L[rr][t] - m); sum += L[rr][t]; }
#pragma unroll
        for (int off = 1; off < 64; off <<= 1) sum += __shfl_xor(sum, off, 64);
        float inv = 1.0f / sum;
        int i = i0 + w * 4 + rr;
        float* arow = attn + ((size_t)bh * S_ + i) * S_;
#pragma unroll
        for (int t = 0; t < 16; ++t)
            arow[t * 64 + lane] = L[rr][t] * inv;
    }
}

// values[b][i][h*64+d] = sum_j attn[bh][i][j] * v[bh][j][d]   (all fp32)
__global__ __launch_bounds__(256) void attn_v(
    const float* __restrict__ attn, const float* __restrict__ v, float* __restrict__ values)
{
    int bh = blockIdx.y;
    int b = bh >> 4, h = bh & 15;
    int i0 = blockIdx.x * 32;
    int tid = threadIdx.x, w = tid >> 6, lane = tid & 63;
    __shared__ float vs[64 * 64];
    __shared__ float as_[32 * 65];
    float acc[8] = {};

    for (int j0 = 0; j0 < S_; j0 += 64) {
        __syncthreads();
        {   // stage v tile 64x64 fp32
            int jl = tid >> 2, c0 = (tid & 3) * 16;
            const float* src = v + ((size_t)bh * S_ + j0 + jl) * 64 + c0;
#pragma unroll
            for (int k = 0; k < 16; k += 4)
                *(float4*)&vs[jl * 64 + c0 + k] = *(const float4*)&src[k];
        }
        {   // stage attn tile 32x64 fp32
            int il = tid >> 3, c0 = (tid & 7) * 8;
            const float* src = attn + ((size_t)bh * S_ + i0 + il) * S_ + j0 + c0;
            float4 r0 = *(const float4*)&src[0];
            float4 r1 = *(const float4*)&src[4];
            as_[il * 65 + c0 + 0] = r0.x; as_[il * 65 + c0 + 1] = r0.y;
            as_[il * 65 + c0 + 2] = r0.z; as_[il * 65 + c0 + 3] = r0.w;
            as_[il * 65 + c0 + 4] = r1.x; as_[il * 65 + c0 + 5] = r1.y;
            as_[il * 65 + c0 + 6] = r1.z; as_[il * 65 + c0 + 7] = r1.w;
        }
        __syncthreads();
#pragma unroll 8
        for (int jj = 0; jj < 64; ++jj) {
            float vv = vs[jj * 64 + lane];
#pragma unroll
            for (int r = 0; r < 8; ++r)
                acc[r] = fmaf(as_[(w * 8 + r) * 65 + jj], vv, acc[r]);
        }
    }
#pragma unroll
    for (int r = 0; r < 8; ++r) {
        int i = i0 + w * 8 + r;
        values[((size_t)(b * S_ + i)) * E_ + h * 64 + lane] = acc[r];
    }
}

extern "C" void kernel_launch(void* const* d_in, const int* in_sizes, int n_in,
                              void* d_out, int out_size, void* d_ws, size_t ws_size,
                              hipStream_t stream)
{
    const float* x  = (const float*)d_in[0];
    const float* W0 = (const float*)d_in[1];
    const float* b0 = (const float*)d_in[2];
    const float* W1 = (const float*)d_in[3];
    const float* b1 = (const float*)d_in[4];
    const float* W2 = (const float*)d_in[5];
    const float* b2 = (const float*)d_in[6];
    const float* Wv = (const float*)d_in[7];
    const float* bv = (const float*)d_in[8];
    const float* Wo = (const float*)d_in[9];
    const float* bo = (const float*)d_in[10];
    const float* A  = (const float*)d_in[11];

    float* out  = (float*)d_out;
    float* attn = out + (size_t)B_ * S_ * E_;   // 4,194,304 then 67,108,864 floats

    // Workspace (floats), ~49 MB total:
    float* p0 = (float*)d_ws;          // p0 -> q (in place); dead after logits
    float* p1 = p0 + 4194304;          // p1; dead after logits -> values alias
    float* vv = p1 + 4194304;          // v, heads layout
    float* t2 = vv + 4194304;          // 64*64
    float* Mm = t2 + 4096;             // 64*64*64
    float* values = p1;                // alias: p1 dead when attn_v runs

    dim3 gg(4096 / 64, 1024 / 64);
    zero_t2<<<64, 64, 0, stream>>>(t2);
    gemm_f32<<<gg, 256, 0, stream>>>(x, W0, b0, p0, nullptr, 0);   // p0 heads
    gemm_f32<<<gg, 256, 0, stream>>>(x, W1, b1, p1, nullptr, 0);   // p1 heads
    gemm_f32<<<gg, 256, 0, stream>>>(x, W2, b2, nullptr, t2, 2);   // t2 fused
    gemm_f32<<<gg, 256, 0, stream>>>(x, Wv, bv, vv, nullptr, 0);   // v heads

    compute_M<<<BH_, 256, 0, stream>>>(A, t2, Mm);
    compute_q<<<dim3(S_ / 16, BH_), 256, 0, stream>>>(p0, Mm);     // q in place
    logits_softmax<<<dim3(S_ / 16, BH_), 256, 0, stream>>>(p0, p1, attn);
    attn_v<<<dim3(S_ / 32, BH_), 256, 0, stream>>>(attn, vv, values);

    gemm_f32<<<gg, 256, 0, stream>>>(values, Wo, bo, out, nullptr, 1);
}

// Round 4
// 752.367 us; speedup vs baseline: 2.1374x; 2.1374x over previous
//
#include <hip/hip_runtime.h>
#include <hip/hip_bf16.h>
#include <cstddef>

#define B_ 4
#define S_ 1024
#define E_ 1024
#define H_ 16
#define D_ 64
#define BH_ (B_*H_)

typedef __attribute__((ext_vector_type(8))) short short8;    // 8 bf16
typedef __attribute__((ext_vector_type(4))) float f32x4;
typedef __attribute__((ext_vector_type(4))) unsigned short us4;
typedef unsigned short u16;

__device__ inline u16 f2b(float x) {
    return __builtin_bit_cast(u16, __float2bfloat16(x));
}
__device__ inline float b2f(u16 u) {
    return __bfloat162float(__builtin_bit_cast(__hip_bfloat16, u));
}
__device__ inline void splitf(float x, u16& h, u16& l) {
    h = f2b(x); l = f2b(x - b2f(h));
}

// ---------------------------------------------------------------------------
// split fp32 array into hi/lo bf16 arrays (n4 = n/4)
// ---------------------------------------------------------------------------
__global__ __launch_bounds__(256) void split_pair(
    const float* __restrict__ in, u16* __restrict__ oh, u16* __restrict__ ol, int n4)
{
    int i = blockIdx.x * 256 + threadIdx.x;
    if (i >= n4) return;
    float4 v = ((const float4*)in)[i];
    us4 h, l;
    splitf(v.x, ((u16*)&h)[0], ((u16*)&l)[0]);
    splitf(v.y, ((u16*)&h)[1], ((u16*)&l)[1]);
    splitf(v.z, ((u16*)&h)[2], ((u16*)&l)[2]);
    splitf(v.w, ((u16*)&h)[3], ((u16*)&l)[3]);
    ((us4*)oh)[i] = h;
    ((us4*)ol)[i] = l;
}

// xsum[b][k] = sum_s x[b,s,k]
__global__ __launch_bounds__(256) void reduce_xsum(
    const float* __restrict__ x, float* __restrict__ xsum)
{
    int b = blockIdx.y;
    int k = blockIdx.x * 256 + threadIdx.x;
    float s = 0.f;
    const float* base = x + (size_t)b * S_ * E_ + k;
    for (int j = 0; j < S_; ++j) s += base[(size_t)j * E_];
    xsum[b * E_ + k] = s;
}

// t2n[b][n] = dot(W2[n], xsum[b]) + S*b2[n]
__global__ __launch_bounds__(256) void compute_t2k(
    const float* __restrict__ W2, const float* __restrict__ b2,
    const float* __restrict__ xsum, float* __restrict__ t2n)
{
    int b = blockIdx.y, n0 = blockIdx.x * 64;
    int w = threadIdx.x >> 6, lane = threadIdx.x & 63;
    const float* xs = xsum + b * E_;
    for (int nn = w; nn < 64; nn += 4) {
        int n = n0 + nn;
        const float* wr = W2 + (size_t)n * E_;
        float s = 0.f;
#pragma unroll
        for (int t = 0; t < 16; ++t) s = fmaf(wr[t * 64 + lane], xs[t * 64 + lane], s);
#pragma unroll
        for (int off = 1; off < 64; off <<= 1) s += __shfl_xor(s, off, 64);
        if (lane == 0) t2n[b * E_ + n] = s + 1024.0f * b2[n];
    }
}

// M[bh][a][c] = (1/8) * sum_d A[a][c][d] * t2[bh][d]
__global__ void compute_M(const float* __restrict__ A, const float* __restrict__ t2n,
                          float* __restrict__ Mout)
{
    int bh = blockIdx.x, b = bh >> 4, h = bh & 15;
    __shared__ float ts[64];
    if (threadIdx.x < 64) ts[threadIdx.x] = t2n[b * E_ + h * 64 + threadIdx.x];
    __syncthreads();
    int c = threadIdx.x & 63;
    int a0 = (threadIdx.x >> 6) * 16;
    for (int a = a0; a < a0 + 16; ++a) {
        float s = 0.f;
        const float* Ap = A + ((size_t)a * 64 + c) * 64;
#pragma unroll 8
        for (int d = 0; d < 64; ++d) s = fmaf(Ap[d], ts[d], s);
        Mout[((size_t)bh * 64 + a) * 64 + c] = s * 0.125f;
    }
}

// ---------------------------------------------------------------------------
// split-bf16 GEMM: C = X*W^T + bias (fp32-accurate via hi/lo, 3 MFMA products)
// X: 4096x1024 (hi/lo bf16 natural), W: 1024x1024 (hi/lo bf16)
// mode 0 (Q):  epilogue computes q = C @ M_bh in-block, writes qh/ql bf16 heads
// mode 1 (P1): writes p1h/p1l bf16 heads layout
// Tile 64x64, 4 waves, wave = 32x32 via 2x2 of 16x16x32.
// ---------------------------------------------------------------------------
__global__ __launch_bounds__(256) void gemm_split(
    const u16* __restrict__ Xh, const u16* __restrict__ Xl,
    const u16* __restrict__ Wh, const u16* __restrict__ Wl,
    const float* __restrict__ bias, const float* __restrict__ Mm,
    u16* __restrict__ oh, u16* __restrict__ ol, int mode)
{
    const int K = 1024;
    __shared__ __align__(16) char smem[34816];
    u16* Xs_h = (u16*)smem;              // [64][40]
    u16* Xs_l = Xs_h + 64 * 40;
    u16* Ws_h = Xs_l + 64 * 40;
    u16* Ws_l = Ws_h + 64 * 40;          // 20480 B
    float* Cs = (float*)smem;            // [64][68] epilogue (a-major, transposed)
    float* Ms = Cs + 64 * 68;            // [64][68]

    const int tid = threadIdx.x;
    const int w = tid >> 6, lane = tid & 63;
    const int waveM = w & 1, waveN = w >> 1;
    const int quad = lane >> 4, l16 = lane & 15;
    const int bm = blockIdx.x, bn = blockIdx.y;

    const int lrow = tid >> 2, lkoff = (tid & 3) * 8;
    const u16* xh_g = Xh + (size_t)(bm * 64 + lrow) * K + lkoff;
    const u16* xl_g = Xl + (size_t)(bm * 64 + lrow) * K + lkoff;
    const u16* wh_g = Wh + (size_t)(bn * 64 + lrow) * K + lkoff;
    const u16* wl_g = Wl + (size_t)(bn * 64 + lrow) * K + lkoff;

    f32x4 acc[2][2] = {};

    for (int k0 = 0; k0 < K; k0 += 32) {
        uint4 a = *(const uint4*)(xh_g + k0);
        uint4 b = *(const uint4*)(xl_g + k0);
        uint4 c = *(const uint4*)(wh_g + k0);
        uint4 d = *(const uint4*)(wl_g + k0);
        __syncthreads();
        *(uint4*)&Xs_h[lrow * 40 + lkoff] = a;
        *(uint4*)&Xs_l[lrow * 40 + lkoff] = b;
        *(uint4*)&Ws_h[lrow * 40 + lkoff] = c;
        *(uint4*)&Ws_l[lrow * 40 + lkoff] = d;
        __syncthreads();

        short8 ah[2], al[2], bh_[2], bl_[2];
#pragma unroll
        for (int mt = 0; mt < 2; ++mt) {
            int r = (waveM * 32 + mt * 16 + l16) * 40 + quad * 8;
            ah[mt] = *(short8*)&Xs_h[r];
            al[mt] = *(short8*)&Xs_l[r];
        }
#pragma unroll
        for (int nt = 0; nt < 2; ++nt) {
            int r = (waveN * 32 + nt * 16 + l16) * 40 + quad * 8;
            bh_[nt] = *(short8*)&Ws_h[r];
            bl_[nt] = *(short8*)&Ws_l[r];
        }
#pragma unroll
        for (int mt = 0; mt < 2; ++mt)
#pragma unroll
            for (int nt = 0; nt < 2; ++nt) {
                acc[mt][nt] = __builtin_amdgcn_mfma_f32_16x16x32_bf16(ah[mt], bh_[nt], acc[mt][nt], 0, 0, 0);
                acc[mt][nt] = __builtin_amdgcn_mfma_f32_16x16x32_bf16(ah[mt], bl_[nt], acc[mt][nt], 0, 0, 0);
                acc[mt][nt] = __builtin_amdgcn_mfma_f32_16x16x32_bf16(al[mt], bh_[nt], acc[mt][nt], 0, 0, 0);
            }
    }

    int b_ = bm >> 4;                 // batch
    int bh = b_ * H_ + bn;            // head = bn (64-wide n-tile)

    if (mode == 1) {                  // p1 -> hi/lo bf16, heads layout
#pragma unroll
        for (int mt = 0; mt < 2; ++mt)
#pragma unroll
            for (int nt = 0; nt < 2; ++nt)
#pragma unroll
                for (int r = 0; r < 4; ++r) {
                    int m = bm * 64 + waveM * 32 + mt * 16 + quad * 4 + r;
                    int n = bn * 64 + waveN * 32 + nt * 16 + l16;
                    float val = acc[mt][nt][r] + bias[n];
                    int s = m & 1023, cc = n & 63;
                    size_t addr = ((size_t)bh * S_ + s) * 64 + cc;
                    u16 hh, ll; splitf(val, hh, ll);
                    oh[addr] = hh; ol[addr] = ll;
                }
        return;
    }

    // mode 0: q = C @ M_bh  (C stored transposed: Cs[a][i])
    __syncthreads();
#pragma unroll
    for (int mt = 0; mt < 2; ++mt)
#pragma unroll
        for (int nt = 0; nt < 2; ++nt)
#pragma unroll
            for (int r = 0; r < 4; ++r) {
                int i = waveM * 32 + mt * 16 + quad * 4 + r;
                int a = waveN * 32 + nt * 16 + l16;
                Cs[a * 68 + i] = acc[mt][nt][r] + bias[bn * 64 + a];
            }
    for (int t = tid; t < 4096; t += 256)
        Ms[(t >> 6) * 68 + (t & 63)] = Mm[(size_t)bh * 4096 + t];
    __syncthreads();

    int tx = tid & 15, ty = tid >> 4;
    float q4[4][4] = {};
    for (int a = 0; a < 64; ++a) {
        float4 cv = *(const float4*)&Cs[a * 68 + ty * 4];
        float4 mv = *(const float4*)&Ms[a * 68 + tx * 4];
        float cm[4] = {cv.x, cv.y, cv.z, cv.w};
        float mm[4] = {mv.x, mv.y, mv.z, mv.w};
#pragma unroll
        for (int ii = 0; ii < 4; ++ii)
#pragma unroll
            for (int cc = 0; cc < 4; ++cc)
                q4[ii][cc] = fmaf(cm[ii], mm[cc], q4[ii][cc]);
    }
    int sbase = (bm & 15) * 64;
#pragma unroll
    for (int ii = 0; ii < 4; ++ii)
#pragma unroll
        for (int cc = 0; cc < 4; ++cc) {
            int s = sbase + ty * 4 + ii, c = tx * 4 + cc;
            size_t addr = ((size_t)bh * S_ + s) * 64 + c;
            u16 hh, ll; splitf(q4[ii][cc], hh, ll);
            oh[addr] = hh; ol[addr] = ll;
        }
}

// ---------------------------------------------------------------------------
// plain bf16 GEMM: X bf16 natural (4096x1024) * W fp32 (cvt in staging) + bias
// mode 0: out bf16 heads layout (v) ; mode 1: out fp32 natural (final)
// ---------------------------------------------------------------------------
__global__ __launch_bounds__(256) void gemm_plain(
    const u16* __restrict__ Xb, const float* __restrict__ Wf,
    const float* __restrict__ bias, u16* __restrict__ outB,
    float* __restrict__ outF, int mode)
{
    const int K = 1024;
    __shared__ __align__(16) u16 Xs[64 * 40];
    __shared__ __align__(16) u16 Ws[64 * 40];

    const int tid = threadIdx.x;
    const int w = tid >> 6, lane = tid & 63;
    const int waveM = w & 1, waveN = w >> 1;
    const int quad = lane >> 4, l16 = lane & 15;
    const int bm = blockIdx.x, bn = blockIdx.y;
    const int lrow = tid >> 2, lkoff = (tid & 3) * 8;

    const u16* xg = Xb + (size_t)(bm * 64 + lrow) * K + lkoff;
    const float* wg = Wf + (size_t)(bn * 64 + lrow) * K + lkoff;

    f32x4 acc[2][2] = {};

    for (int k0 = 0; k0 < K; k0 += 32) {
        uint4 xv = *(const uint4*)(xg + k0);
        float4 w0 = *(const float4*)(wg + k0);
        float4 w1 = *(const float4*)(wg + k0 + 4);
        short8 wp;
        ((u16*)&wp)[0] = f2b(w0.x); ((u16*)&wp)[1] = f2b(w0.y);
        ((u16*)&wp)[2] = f2b(w0.z); ((u16*)&wp)[3] = f2b(w0.w);
        ((u16*)&wp)[4] = f2b(w1.x); ((u16*)&wp)[5] = f2b(w1.y);
        ((u16*)&wp)[6] = f2b(w1.z); ((u16*)&wp)[7] = f2b(w1.w);
        __syncthreads();
        *(uint4*)&Xs[lrow * 40 + lkoff] = xv;
        *(short8*)&Ws[lrow * 40 + lkoff] = wp;
        __syncthreads();

        short8 af[2], bf_[2];
#pragma unroll
        for (int mt = 0; mt < 2; ++mt)
            af[mt] = *(short8*)&Xs[(waveM * 32 + mt * 16 + l16) * 40 + quad * 8];
#pragma unroll
        for (int nt = 0; nt < 2; ++nt)
            bf_[nt] = *(short8*)&Ws[(waveN * 32 + nt * 16 + l16) * 40 + quad * 8];
#pragma unroll
        for (int mt = 0; mt < 2; ++mt)
#pragma unroll
            for (int nt = 0; nt < 2; ++nt)
                acc[mt][nt] = __builtin_amdgcn_mfma_f32_16x16x32_bf16(af[mt], bf_[nt], acc[mt][nt], 0, 0, 0);
    }

#pragma unroll
    for (int mt = 0; mt < 2; ++mt)
#pragma unroll
        for (int nt = 0; nt < 2; ++nt)
#pragma unroll
            for (int r = 0; r < 4; ++r) {
                int m = bm * 64 + waveM * 32 + mt * 16 + quad * 4 + r;
                int n = bn * 64 + waveN * 32 + nt * 16 + l16;
                float val = acc[mt][nt][r] + bias[n];
                if (mode == 0) {
                    int b = m >> 10, s = m & 1023, h = n >> 6, c = n & 63;
                    outB[((size_t)(b * H_ + h) * S_ + s) * 64 + c] = f2b(val);
                } else {
                    outF[(size_t)m * 1024 + n] = val;
                }
            }
}

// ---------------------------------------------------------------------------
// logits = q*p1^T (split-bf16 MFMA), softmax over j, write fp32 attn.
// Block: 16 i-rows of one bh; wave w covers j-cols {64t + 16w + l16}.
// ---------------------------------------------------------------------------
__global__ __launch_bounds__(256) void logits_softmax_mfma(
    const u16* __restrict__ qh, const u16* __restrict__ ql,
    const u16* __restrict__ p1h, const u16* __restrict__ p1l,
    float* __restrict__ attn)
{
    int bh = blockIdx.y, i0 = blockIdx.x * 16;
    int tid = threadIdx.x, w = tid >> 6, lane = tid & 63;
    int quad = lane >> 4, l16 = lane & 15;

    __shared__ __align__(16) u16 qhs[16 * 72], qls[16 * 72];
    __shared__ __align__(16) u16 p1hs[64 * 72], p1ls[64 * 72];
    __shared__ float redm[4][16], reds[4][16];

    {   // stage q (16x64 hi/lo)
        int row = tid >> 4, c0 = (tid & 15) * 4;
        size_t g = ((size_t)bh * S_ + i0 + row) * 64 + c0;
        *(us4*)&qhs[row * 72 + c0] = *(const us4*)&qh[g];
        *(us4*)&qls[row * 72 + c0] = *(const us4*)&ql[g];
    }
    __syncthreads();

    short8 ah[2], al[2];
#pragma unroll
    for (int ch = 0; ch < 2; ++ch) {
        ah[ch] = *(short8*)&qhs[l16 * 72 + ch * 32 + quad * 8];
        al[ch] = *(short8*)&qls[l16 * 72 + ch * 32 + quad * 8];
    }

    f32x4 L[16];
    for (int t = 0; t < 16; ++t) {
        __syncthreads();
        {   // stage p1 rows t*64 .. t*64+63 (hi/lo)
            int jl = tid >> 2, c0 = (tid & 3) * 16;
            size_t g = ((size_t)bh * S_ + t * 64 + jl) * 64 + c0;
            *(uint4*)&p1hs[jl * 72 + c0]     = *(const uint4*)&p1h[g];
            *(uint4*)&p1hs[jl * 72 + c0 + 8] = *(const uint4*)&p1h[g + 8];
            *(uint4*)&p1ls[jl * 72 + c0]     = *(const uint4*)&p1l[g];
            *(uint4*)&p1ls[jl * 72 + c0 + 8] = *(const uint4*)&p1l[g + 8];
        }
        __syncthreads();
        int jr = w * 16 + l16;
        short8 bh0 = *(short8*)&p1hs[jr * 72 + quad * 8];
        short8 bh1 = *(short8*)&p1hs[jr * 72 + 32 + quad * 8];
        short8 bl0 = *(short8*)&p1ls[jr * 72 + quad * 8];
        short8 bl1 = *(short8*)&p1ls[jr * 72 + 32 + quad * 8];
        f32x4 a = {};
        a = __builtin_amdgcn_mfma_f32_16x16x32_bf16(ah[0], bh0, a, 0, 0, 0);
        a = __builtin_amdgcn_mfma_f32_16x16x32_bf16(ah[1], bh1, a, 0, 0, 0);
        a = __builtin_amdgcn_mfma_f32_16x16x32_bf16(ah[0], bl0, a, 0, 0, 0);
        a = __builtin_amdgcn_mfma_f32_16x16x32_bf16(ah[1], bl1, a, 0, 0, 0);
        a = __builtin_amdgcn_mfma_f32_16x16x32_bf16(al[0], bh0, a, 0, 0, 0);
        a = __builtin_amdgcn_mfma_f32_16x16x32_bf16(al[1], bh1, a, 0, 0, 0);
        L[t] = a;
    }

    // softmax: lane holds rows quad*4+r, cols {64t + 16w + l16}
    float mrow[4], srow[4];
#pragma unroll
    for (int r = 0; r < 4; ++r) {
        float m = L[0][r];
#pragma unroll
        for (int t = 1; t < 16; ++t) m = fmaxf(m, L[t][r]);
#pragma unroll
        for (int off = 1; off < 16; off <<= 1) m = fmaxf(m, __shfl_xor(m, off, 64));
        mrow[r] = m;
    }
    if (l16 == 0)
#pragma unroll
        for (int r = 0; r < 4; ++r) redm[w][quad * 4 + r] = mrow[r];
    __syncthreads();
#pragma unroll
    for (int r = 0; r < 4; ++r) {
        int row = quad * 4 + r;
        float m = fmaxf(fmaxf(redm[0][row], redm[1][row]), fmaxf(redm[2][row], redm[3][row]));
        float s = 0.f;
#pragma unroll
        for (int t = 0; t < 16; ++t) { L[t][r] = __expf(L[t][r] - m); s += L[t][r]; }
#pragma unroll
        for (int off = 1; off < 16; off <<= 1) s += __shfl_xor(s, off, 64);
        srow[r] = s;
    }
    if (l16 == 0)
#pragma unroll
        for (int r = 0; r < 4; ++r) reds[w][quad * 4 + r] = srow[r];
    __syncthreads();
#pragma unroll
    for (int r = 0; r < 4; ++r) {
        int row = quad * 4 + r;
        float inv = 1.0f / (reds[0][row] + reds[1][row] + reds[2][row] + reds[3][row]);
        float* arow = attn + ((size_t)bh * S_ + i0 + row) * S_;
#pragma unroll
        for (int t = 0; t < 16; ++t)
            arow[t * 64 + w * 16 + l16] = L[t][r] * inv;
    }
}

// ---------------------------------------------------------------------------
// values = attn @ v  (MFMA bf16; attn fp32 -> bf16 in staging; v via fp32-LDS
// transpose, stride 33 to dodge bank conflicts). values bf16 natural layout.
// ---------------------------------------------------------------------------
__global__ __launch_bounds__(256) void attn_v_mfma(
    const float* __restrict__ attn, const u16* __restrict__ vb,
    u16* __restrict__ values)
{
    int bh = blockIdx.y, b = bh >> 4, h = bh & 15;
    int i0 = blockIdx.x * 64;
    int tid = threadIdx.x, w = tid >> 6, lane = tid & 63;
    int quad = lane >> 4, l16 = lane & 15;

    __shared__ __align__(16) u16 as_[64 * 40];
    __shared__ float vt[64 * 33];
    f32x4 acc[4] = {};

    for (int j0 = 0; j0 < S_; j0 += 32) {
        __syncthreads();
        {   // attn tile 64x32 fp32 -> bf16 LDS
            int row = tid >> 2, c0 = (tid & 3) * 8;
            const float* src = attn + ((size_t)bh * S_ + i0 + row) * S_ + j0 + c0;
            float4 v0 = *(const float4*)&src[0];
            float4 v1 = *(const float4*)&src[4];
            short8 p;
            ((u16*)&p)[0] = f2b(v0.x); ((u16*)&p)[1] = f2b(v0.y);
            ((u16*)&p)[2] = f2b(v0.z); ((u16*)&p)[3] = f2b(v0.w);
            ((u16*)&p)[4] = f2b(v1.x); ((u16*)&p)[5] = f2b(v1.y);
            ((u16*)&p)[6] = f2b(v1.z); ((u16*)&p)[7] = f2b(v1.w);
            *(short8*)&as_[row * 40 + c0] = p;
        }
        {   // v tile 32x64 bf16 -> fp32 transposed vt[d][j], stride 33
            int jr = tid >> 3, d0 = (tid & 7) * 8;
            const u16* src = vb + ((size_t)bh * S_ + j0 + jr) * 64 + d0;
            uint4 raw = *(const uint4*)src;
            const u16* rb = (const u16*)&raw;
#pragma unroll
            for (int k = 0; k < 8; ++k)
                vt[(d0 + k) * 33 + jr] = b2f(rb[k]);
        }
        __syncthreads();

        short8 afr = *(short8*)&as_[(w * 16 + l16) * 40 + quad * 8];
#pragma unroll
        for (int dt = 0; dt < 4; ++dt) {
            const float* col = &vt[(dt * 16 + l16) * 33 + quad * 8];
            short8 bfr;
#pragma unroll
            for (int jj = 0; jj < 8; ++jj) ((u16*)&bfr)[jj] = f2b(col[jj]);
            acc[dt] = __builtin_amdgcn_mfma_f32_16x16x32_bf16(afr, bfr, acc[dt], 0, 0, 0);
        }
    }
#pragma unroll
    for (int dt = 0; dt < 4; ++dt)
#pragma unroll
        for (int r = 0; r < 4; ++r) {
            int i = i0 + w * 16 + quad * 4 + r;
            int d = dt * 16 + l16;
            values[((size_t)(b * S_ + i)) * E_ + h * 64 + d] = f2b(acc[dt][r]);
        }
}

extern "C" void kernel_launch(void* const* d_in, const int* in_sizes, int n_in,
                              void* d_out, int out_size, void* d_ws, size_t ws_size,
                              hipStream_t stream)
{
    const float* x  = (const float*)d_in[0];
    const float* W0 = (const float*)d_in[1];
    const float* b0 = (const float*)d_in[2];
    const float* W1 = (const float*)d_in[3];
    const float* b1 = (const float*)d_in[4];
    const float* W2 = (const float*)d_in[5];
    const float* b2 = (const float*)d_in[6];
    const float* Wv = (const float*)d_in[7];
    const float* bv = (const float*)d_in[8];
    const float* Wo = (const float*)d_in[9];
    const float* bo = (const float*)d_in[10];
    const float* A  = (const float*)d_in[11];

    float* out  = (float*)d_out;
    float* attn = out + (size_t)B_ * S_ * E_;

    // workspace (~57 MB)
    u16* xh  = (u16*)d_ws;                 // 8 MB -> values (after v GEMM)
    u16* xl  = xh + 4194304;               // 8 MB -> vb (after p1 GEMM)
    u16* w0h = xl + 4194304;               // 2 MB
    u16* w0l = w0h + 1048576;
    u16* w1h = w0l + 1048576;
    u16* w1l = w1h + 1048576;              // -> 24 MB
    u16* qh  = w1l + 1048576;              // 8 MB
    u16* ql  = qh + 4194304;               // 8 MB
    u16* p1h = ql + 4194304;               // 8 MB
    u16* p1l = p1h + 4194304;              // 8 MB -> 56 MB
    float* xsum = (float*)(p1l + 4194304); // 4096
    float* t2n  = xsum + 4096;             // 4096
    float* Mm   = t2n + 4096;              // 262144 -> ~57.1 MB
    u16* vb     = xl;                      // alias
    u16* values = xh;                      // alias

    split_pair<<<4096, 256, 0, stream>>>(x, xh, xl, 1048576);
    split_pair<<<1024, 256, 0, stream>>>(W0, w0h, w0l, 262144);
    split_pair<<<1024, 256, 0, stream>>>(W1, w1h, w1l, 262144);
    reduce_xsum<<<dim3(4, 4), 256, 0, stream>>>(x, xsum);
    compute_t2k<<<dim3(16, 4), 256, 0, stream>>>(W2, b2, xsum, t2n);
    compute_M<<<BH_, 256, 0, stream>>>(A, t2n, Mm);

    dim3 gg(64, 16);
    gemm_split<<<gg, 256, 0, stream>>>(xh, xl, w0h, w0l, b0, Mm, qh, ql, 0);   // q
    gemm_split<<<gg, 256, 0, stream>>>(xh, xl, w1h, w1l, b1, nullptr, p1h, p1l, 1); // p1
    gemm_plain<<<gg, 256, 0, stream>>>(xh, Wv, bv, vb, nullptr, 0);            // v

    logits_softmax_mfma<<<dim3(64, 64), 256, 0, stream>>>(qh, ql, p1h, p1l, attn);
    attn_v_mfma<<<dim3(16, 64), 256, 0, stream>>>(attn, vb, values);

    gemm_plain<<<gg, 256, 0, stream>>>(values, Wo, bo, nullptr, out, 1);
}